// Round 1
// baseline (643.385 us; speedup 1.0000x reference)
//
#include <hip/hip_runtime.h>

typedef unsigned short u16;
typedef unsigned int u32;
typedef __attribute__((ext_vector_type(8))) short short8;
typedef __attribute__((ext_vector_type(4))) float floatx4;

// ---------- bf16 helpers (manual, header-version independent) ----------
__device__ __forceinline__ float b2f(u32 bits16) {
    union { u32 u; float f; } c; c.u = bits16 << 16; return c.f;
}
__device__ __forceinline__ u16 f2b(float f) {
    union { float f; u32 u; } c; c.f = f;
    u32 u = c.u;
    return (u16)((u + 0x7FFFu + ((u >> 16) & 1u)) >> 16);   // RNE
}
__device__ __forceinline__ u32 pkmul(u32 a, u32 b) {
    float a0 = b2f(a & 0xFFFFu), a1 = b2f(a >> 16);
    float b0 = b2f(b & 0xFFFFu), b1 = b2f(b >> 16);
    return (u32)f2b(a0 * b0) | ((u32)f2b(a1 * b1) << 16);
}

// ---------- graph prep ----------
__global__ __launch_bounds__(256) void count_deg(const int* __restrict__ row, int* __restrict__ cnt, int E) {
    int e = blockIdx.x * 256 + threadIdx.x;
    if (e < E) atomicAdd(&cnt[row[e]], 1);
}

// single block: exclusive prefix sum of cnt -> offs, dinv = (cnt+1)^-0.5
__global__ __launch_bounds__(1024) void scan_offsets(const int* __restrict__ cnt, int* __restrict__ offs,
                                                     float* __restrict__ dinv, int N, int E) {
    __shared__ int sc[1024];
    int t = threadIdx.x;
    int per = (N + 1023) >> 10;
    int s0 = t * per, s1 = min(s0 + per, N);
    int s = 0;
    for (int i = s0; i < s1; i++) s += cnt[i];
    sc[t] = s;
    __syncthreads();
    for (int o = 1; o < 1024; o <<= 1) {
        int v = (t >= o) ? sc[t - o] : 0;
        __syncthreads();
        sc[t] += v;
        __syncthreads();
    }
    int run = sc[t] - s;   // exclusive
    for (int i = s0; i < s1; i++) {
        offs[i] = run;
        run += cnt[i];
        dinv[i] = rsqrtf((float)cnt[i] + 1.0f);
    }
    if (t == 0) offs[N] = E;
}

__global__ __launch_bounds__(256) void sort_edges(const int* __restrict__ row, const int* __restrict__ col,
                                                  const int* __restrict__ offs, int* __restrict__ cursor,
                                                  int* __restrict__ scol, int E) {
    int e = blockIdx.x * 256 + threadIdx.x;
    if (e < E) {
        int r = row[e];
        int p = offs[r] + atomicAdd(&cursor[r], 1);
        scol[p] = col[e];
    }
}

// ---------- weight prep: WT[which][n][k] = bf16(W[k][n]) ----------
__global__ __launch_bounds__(256) void prep_w(const float* __restrict__ W1, const float* __restrict__ W2,
                                              const float* __restrict__ pW1, u16* __restrict__ WT) {
    int tid = blockIdx.x * 256 + threadIdx.x;       // 0..196607
    int which = tid >> 16, id = tid & 65535;
    int n = id >> 8, k = id & 255;
    const float* W = (which == 0) ? W1 : ((which == 1) ? W2 : pW1);
    WT[tid] = f2b(W[k * 256 + n]);
}

// ---------- h0 = bf16(concat(emb, x)) ----------
__global__ __launch_bounds__(256) void concat_h0(const float* __restrict__ emb, const float* __restrict__ x,
                                                 u16* __restrict__ h0b, int N) {
    int t = blockIdx.x * 256 + threadIdx.x;
    long base = (long)t * 4;
    if (base >= (long)N * 256) return;
    int i = (int)(base >> 8), k = (int)(base & 255);
    const float* src = (k < 128) ? (emb + (long)i * 128 + k) : (x + (long)i * 128 + (k - 128));
    float4 v = *(const float4*)src;
    ushort4 o;
    o.x = f2b(v.x); o.y = f2b(v.y); o.z = f2b(v.z); o.w = f2b(v.w);
    *(ushort4*)(h0b + base) = o;
}

// ---------- GEMM: C[M][256] = A_bf16[M][256] @ B, with BT_bf16[n][k] ----------
// block: 256 thr = 4 waves, tile 64(M) x 256(N), BK=64
__global__ __launch_bounds__(256) void gemm_k256(const u16* __restrict__ A, const u16* __restrict__ BT,
                                                 float* __restrict__ C, int M) {
    __shared__ u16 As[64 * 72];     // +8 pad: 2-way banks only
    __shared__ u16 Bs[256 * 72];
    int tid = threadIdx.x;
    int wave = tid >> 6, lane = tid & 63, l15 = lane & 15, quad = lane >> 4;
    int row0 = blockIdx.x * 64;
    floatx4 acc[16];
    floatx4 zero = {0.f, 0.f, 0.f, 0.f};
#pragma unroll
    for (int i = 0; i < 16; i++) acc[i] = zero;

    int ar = tid >> 2, aseg = (tid & 3) * 16;
    int agrow = min(row0 + ar, M - 1);

    for (int k0 = 0; k0 < 256; k0 += 64) {
        {   // stage A: 16 bf16 per thread (2x uint4)
            const uint4* s = (const uint4*)(A + (long)agrow * 256 + k0 + aseg);
            uint4* d = (uint4*)(As + ar * 72 + aseg);
            d[0] = s[0]; d[1] = s[1];
        }
        {   // stage B: thread t = n-row, 64 bf16 (8x uint4)
            const uint4* s = (const uint4*)(BT + (long)tid * 256 + k0);
            uint4* d = (uint4*)(Bs + tid * 72);
#pragma unroll
            for (int i = 0; i < 8; i++) d[i] = s[i];
        }
        __syncthreads();
#pragma unroll
        for (int kk = 0; kk < 64; kk += 32) {
            short8 a = *(const short8*)(As + (wave * 16 + l15) * 72 + kk + quad * 8);
#pragma unroll
            for (int nt = 0; nt < 16; nt++) {
                short8 b = *(const short8*)(Bs + (nt * 16 + l15) * 72 + kk + quad * 8);
                acc[nt] = __builtin_amdgcn_mfma_f32_16x16x32_bf16(a, b, acc[nt], 0, 0, 0);
            }
        }
        __syncthreads();
    }
    int mb = row0 + wave * 16 + quad * 4;
#pragma unroll
    for (int nt = 0; nt < 16; nt++) {
        int colc = nt * 16 + l15;
#pragma unroll
        for (int r = 0; r < 4; r++) {
            int mm = mb + r;
            if (mm < M) C[(long)mm * 256 + colc] = acc[nt][r];
        }
    }
}

// ---------- aggregation: h[i] = dinv_i*(sum_c dinv_c*m[c] + dinv_i*m[i]) + b ----------
template <int BF16OUT>
__global__ __launch_bounds__(256) void aggregate(const float* __restrict__ m, const int* __restrict__ offs,
                                                 const int* __restrict__ scol, const float* __restrict__ dinv,
                                                 const float* __restrict__ bias, void* __restrict__ out, int N) {
    int node = blockIdx.x * 4 + (threadIdx.x >> 6);
    int lane = threadIdx.x & 63;
    if (node >= N) return;
    int beg = offs[node], end = offs[node + 1];
    float4 acc = make_float4(0.f, 0.f, 0.f, 0.f);
    for (int j = beg; j < end; j++) {
        int c = scol[j];
        float dc = dinv[c];
        float4 v = *(const float4*)(m + (long)c * 256 + lane * 4);
        acc.x = fmaf(v.x, dc, acc.x);
        acc.y = fmaf(v.y, dc, acc.y);
        acc.z = fmaf(v.z, dc, acc.z);
        acc.w = fmaf(v.w, dc, acc.w);
    }
    float di = dinv[node];
    float4 mv = *(const float4*)(m + (long)node * 256 + lane * 4);
    float4 b = *(const float4*)(bias + lane * 4);
    float4 h;
    h.x = fmaf(di, fmaf(di, mv.x, acc.x), b.x);
    h.y = fmaf(di, fmaf(di, mv.y, acc.y), b.y);
    h.z = fmaf(di, fmaf(di, mv.z, acc.z), b.z);
    h.w = fmaf(di, fmaf(di, mv.w, acc.w), b.w);
    if (BF16OUT) {
        ushort4 o;
        o.x = f2b(h.x); o.y = f2b(h.y); o.z = f2b(h.z); o.w = f2b(h.w);
        *(ushort4*)((u16*)out + (long)node * 256 + lane * 4) = o;
    } else {
        *(float4*)((float*)out + (long)node * 256 + lane * 4) = h;
    }
}

// ---------- BN stats: per-block partial column sums ----------
__global__ __launch_bounds__(256) void bn_stats(const float* __restrict__ h, float* __restrict__ sums, int N) {
    int j = threadIdx.x;                 // feature 0..255
    int r0 = blockIdx.x * 64;
    int r1 = min(r0 + 64, N);
    float s = 0.f, s2 = 0.f;
    for (int r = r0; r < r1; r++) {
        float v = h[(long)r * 256 + j];
        s += v;
        s2 = fmaf(v, v, s2);
    }
    unsafeAtomicAdd(&sums[j], s);
    unsafeAtomicAdd(&sums[256 + j], s2);
}

// ---------- BN apply + ReLU -> bf16 ----------
__global__ __launch_bounds__(256) void bn_apply(const float* __restrict__ h, const float* __restrict__ sums,
                                                const float* __restrict__ gamma, const float* __restrict__ beta,
                                                u16* __restrict__ hb, int N) {
    int t = blockIdx.x * 256 + threadIdx.x;
    long base = (long)t * 4;
    if (base >= (long)N * 256) return;
    int k = (int)(base & 255);
    float invN = 1.0f / (float)N;
    float4 v = *(const float4*)(h + base);
    ushort4 o;
    float vv[4] = {v.x, v.y, v.z, v.w};
    u16 ob[4];
#pragma unroll
    for (int i = 0; i < 4; i++) {
        int kk = k + i;
        float mean = sums[kk] * invN;
        float var = sums[256 + kk] * invN - mean * mean;
        float rs = rsqrtf(var + 1e-5f);
        float val = (vv[i] - mean) * rs * gamma[kk] + beta[kk];
        ob[i] = f2b(fmaxf(val, 0.f));
    }
    o.x = ob[0]; o.y = ob[1]; o.z = ob[2]; o.w = ob[3];
    *(ushort4*)(hb + base) = o;
}

// ---------- fused link predictor ----------
// block = 64 queries; Z built in LDS from h2 gathers; MFMA vs pW1T; epilogue relu*pW2 + sigmoid
__global__ __launch_bounds__(256) void predictor(const u16* __restrict__ h2b, const int* __restrict__ e0,
                                                 const int* __restrict__ e1, const u16* __restrict__ pW1T,
                                                 const float* __restrict__ pb1, const float* __restrict__ pW2,
                                                 const float* __restrict__ pb2, float* __restrict__ out, int Q) {
    __shared__ u16 Zs[64 * 264];   // 64 rows x 256 k (+8 pad)
    __shared__ u16 Bs[256 * 40];   // 256 n x 32 k (+8 pad)
    int tid = threadIdx.x;
    int wave = tid >> 6, lane = tid & 63, l15 = lane & 15, quad = lane >> 4;
    int q0 = blockIdx.x * 64;
    {   // stage Z: thread t -> (row = t/4, k-seg 64)
        int row = tid >> 2, seg = (tid & 3) * 64;
        int q = min(q0 + row, Q - 1);
        long u = e0[q], v = e1[q];
        const uint4* pu = (const uint4*)(h2b + u * 256 + seg);
        const uint4* pv = (const uint4*)(h2b + v * 256 + seg);
        uint4* pz = (uint4*)(Zs + row * 264 + seg);
#pragma unroll
        for (int i = 0; i < 8; i++) {
            uint4 a = pu[i], b = pv[i];
            uint4 z;
            z.x = pkmul(a.x, b.x);
            z.y = pkmul(a.y, b.y);
            z.z = pkmul(a.z, b.z);
            z.w = pkmul(a.w, b.w);
            pz[i] = z;
        }
    }
    floatx4 acc[16];
    floatx4 zero = {0.f, 0.f, 0.f, 0.f};
#pragma unroll
    for (int i = 0; i < 16; i++) acc[i] = zero;

    for (int k0 = 0; k0 < 256; k0 += 32) {
        {   // stage Bs: thread t = n-row, 32 bf16 (4x uint4)
            const uint4* s = (const uint4*)(pW1T + (long)tid * 256 + k0);
            uint4* d = (uint4*)(Bs + tid * 40);
            d[0] = s[0]; d[1] = s[1]; d[2] = s[2]; d[3] = s[3];
        }
        __syncthreads();
        short8 a = *(const short8*)(Zs + (wave * 16 + l15) * 264 + k0 + quad * 8);
#pragma unroll
        for (int nt = 0; nt < 16; nt++) {
            short8 b = *(const short8*)(Bs + (nt * 16 + l15) * 40 + quad * 8);
            acc[nt] = __builtin_amdgcn_mfma_f32_16x16x32_bf16(a, b, acc[nt], 0, 0, 0);
        }
        __syncthreads();
    }
    // epilogue: out[q] = sigmoid( sum_n relu(z1[q][n]) * pW2[n] + pb2 )
    float rs0 = 0.f, rs1 = 0.f, rs2 = 0.f, rs3 = 0.f;
#pragma unroll
    for (int nt = 0; nt < 16; nt++) {
        int colc = nt * 16 + l15;
        float w2 = pW2[colc], bb = pb1[colc];
        float z;
        z = acc[nt][0] + bb; rs0 = fmaf(fmaxf(z, 0.f), w2, rs0);
        z = acc[nt][1] + bb; rs1 = fmaf(fmaxf(z, 0.f), w2, rs1);
        z = acc[nt][2] + bb; rs2 = fmaf(fmaxf(z, 0.f), w2, rs2);
        z = acc[nt][3] + bb; rs3 = fmaf(fmaxf(z, 0.f), w2, rs3);
    }
#pragma unroll
    for (int m = 1; m < 16; m <<= 1) {
        rs0 += __shfl_xor(rs0, m, 64);
        rs1 += __shfl_xor(rs1, m, 64);
        rs2 += __shfl_xor(rs2, m, 64);
        rs3 += __shfl_xor(rs3, m, 64);
    }
    if (l15 == 0) {
        int qb = q0 + wave * 16 + quad * 4;
        float b2v = pb2[0];
        float rr[4] = {rs0, rs1, rs2, rs3};
#pragma unroll
        for (int r = 0; r < 4; r++) {
            int q = qb + r;
            if (q < Q) out[q] = 1.0f / (1.0f + __expf(-(rr[r] + b2v)));
        }
    }
}

extern "C" void kernel_launch(void* const* d_in, const int* in_sizes, int n_in,
                              void* d_out, int out_size, void* d_ws, size_t ws_size,
                              hipStream_t stream) {
    const float* x      = (const float*)d_in[0];
    const int*   adj_row= (const int*)d_in[1];
    const int*   adj_col= (const int*)d_in[2];
    const int*   edges  = (const int*)d_in[3];
    const float* emb    = (const float*)d_in[4];
    const float* W1     = (const float*)d_in[5];
    const float* b1     = (const float*)d_in[6];
    const float* W2     = (const float*)d_in[7];
    const float* b2     = (const float*)d_in[8];
    const float* gamma  = (const float*)d_in[9];
    const float* beta   = (const float*)d_in[10];
    const float* pW1    = (const float*)d_in[11];
    const float* pb1    = (const float*)d_in[12];
    const float* pW2    = (const float*)d_in[13];
    const float* pb2    = (const float*)d_in[14];
    float* out = (float*)d_out;

    int N = in_sizes[0] / 128;
    int E = in_sizes[1];
    int Q = in_sizes[3] / 2;

    char* ws = (char*)d_ws;
    size_t off = 0;
    auto alloc = [&](size_t bytes) -> char* {
        char* p = ws + off;
        off += (bytes + 255) & ~(size_t)255;
        return p;
    };
    int*   deg_cnt = (int*)alloc((size_t)N * 4);
    int*   offs    = (int*)alloc((size_t)(N + 1) * 4);
    int*   cursor  = (int*)alloc((size_t)N * 4);
    float* dinv    = (float*)alloc((size_t)N * 4);
    int*   scol    = (int*)alloc((size_t)E * 4);
    float* sums    = (float*)alloc(512 * 4);
    u16*   WT      = (u16*)alloc((size_t)3 * 65536 * 2);
    u16*   hb      = (u16*)alloc((size_t)N * 256 * 2);   // h0b, later h1b
    float* m       = (float*)alloc((size_t)N * 256 * 4); // m1, later m2
    float* hraw    = (float*)alloc((size_t)N * 256 * 4); // h1raw, later h2b
    u16*   h2b     = (u16*)hraw;

    hipMemsetAsync(deg_cnt, 0, (size_t)N * 4, stream);
    hipMemsetAsync(cursor, 0, (size_t)N * 4, stream);
    hipMemsetAsync(sums, 0, 512 * 4, stream);

    int eb  = (E + 255) / 256;
    int nb4 = (N * 64 + 255) / 256;   // N*256/4 threads
    int gb  = (N + 63) / 64;
    int ab  = (N + 3) / 4;

    count_deg<<<eb, 256, 0, stream>>>(adj_row, deg_cnt, E);
    scan_offsets<<<1, 1024, 0, stream>>>(deg_cnt, offs, dinv, N, E);
    sort_edges<<<eb, 256, 0, stream>>>(adj_row, adj_col, offs, cursor, scol, E);
    prep_w<<<768, 256, 0, stream>>>(W1, W2, pW1, WT);
    concat_h0<<<nb4, 256, 0, stream>>>(emb, x, hb, N);

    gemm_k256<<<gb, 256, 0, stream>>>(hb, WT, m, N);                       // m1 = h0 @ W1
    aggregate<0><<<ab, 256, 0, stream>>>(m, offs, scol, dinv, b1, hraw, N); // h1raw
    bn_stats<<<(N + 63) / 64, 256, 0, stream>>>(hraw, sums, N);
    bn_apply<<<nb4, 256, 0, stream>>>(hraw, sums, gamma, beta, hb, N);      // h1b (bf16)
    gemm_k256<<<gb, 256, 0, stream>>>(hb, WT + 65536, m, N);               // m2 = h1 @ W2
    aggregate<1><<<ab, 256, 0, stream>>>(m, offs, scol, dinv, b2, h2b, N);  // h2b (bf16)
    predictor<<<(Q + 63) / 64, 256, 0, stream>>>(h2b, edges, edges + Q,
                                                 WT + 131072, pb1, pW2, pb2, out, Q);
}

// Round 2
// 598.247 us; speedup vs baseline: 1.0755x; 1.0755x over previous
//
#include <hip/hip_runtime.h>

typedef unsigned short u16;
typedef unsigned int u32;
typedef __attribute__((ext_vector_type(8))) short short8;
typedef __attribute__((ext_vector_type(4))) float floatx4;

// ---------- bf16 helpers ----------
__device__ __forceinline__ float b2f(u32 bits16) {
    union { u32 u; float f; } c; c.u = bits16 << 16; return c.f;
}
__device__ __forceinline__ u16 f2b(float f) {
    union { float f; u32 u; } c; c.f = f;
    u32 u = c.u;
    return (u16)((u + 0x7FFFu + ((u >> 16) & 1u)) >> 16);   // RNE
}
__device__ __forceinline__ u32 pkmul(u32 a, u32 b) {
    float a0 = b2f(a & 0xFFFFu), a1 = b2f(a >> 16);
    float b0 = b2f(b & 0xFFFFu), b1 = b2f(b >> 16);
    return (u32)f2b(a0 * b0) | ((u32)f2b(a1 * b1) << 16);
}

// ---------- graph prep ----------
__global__ __launch_bounds__(256) void count_deg(const int* __restrict__ row, int* __restrict__ cnt, int E) {
    int e = blockIdx.x * 256 + threadIdx.x;
    if (e < E) atomicAdd(&cnt[row[e]], 1);
}

__global__ __launch_bounds__(1024) void scan_offsets(const int* __restrict__ cnt, int* __restrict__ offs,
                                                     float* __restrict__ dinv, int N, int E) {
    __shared__ int sc[1024];
    int t = threadIdx.x;
    int per = (N + 1023) >> 10;
    int s0 = t * per, s1 = min(s0 + per, N);
    int s = 0;
    for (int i = s0; i < s1; i++) s += cnt[i];
    sc[t] = s;
    __syncthreads();
    for (int o = 1; o < 1024; o <<= 1) {
        int v = (t >= o) ? sc[t - o] : 0;
        __syncthreads();
        sc[t] += v;
        __syncthreads();
    }
    int run = sc[t] - s;   // exclusive
    for (int i = s0; i < s1; i++) {
        offs[i] = run;
        run += cnt[i];
        dinv[i] = rsqrtf((float)cnt[i] + 1.0f);
    }
    if (t == 0) offs[N] = E;
}

__global__ __launch_bounds__(256) void sort_edges(const int* __restrict__ row, const int* __restrict__ col,
                                                  const int* __restrict__ offs, int* __restrict__ cursor,
                                                  int* __restrict__ scol, int E) {
    int e = blockIdx.x * 256 + threadIdx.x;
    if (e < E) {
        int r = row[e];
        int p = offs[r] + atomicAdd(&cursor[r], 1);
        scol[p] = col[e];
    }
}

// ---------- weight prep: WT[which][n][k] = bf16(W[k][n]) ----------
__global__ __launch_bounds__(256) void prep_w(const float* __restrict__ W1, const float* __restrict__ W2,
                                              const float* __restrict__ pW1, u16* __restrict__ WT) {
    int tid = blockIdx.x * 256 + threadIdx.x;       // 0..196607
    int which = tid >> 16, id = tid & 65535;
    int n = id >> 8, k = id & 255;
    const float* W = (which == 0) ? W1 : ((which == 1) ? W2 : pW1);
    WT[tid] = f2b(W[k * 256 + n]);
}

// ---------- h0 = bf16(concat(emb, x)) ----------
__global__ __launch_bounds__(256) void concat_h0(const float* __restrict__ emb, const float* __restrict__ x,
                                                 u16* __restrict__ h0b, int N) {
    int t = blockIdx.x * 256 + threadIdx.x;
    long base = (long)t * 4;
    if (base >= (long)N * 256) return;
    int i = (int)(base >> 8), k = (int)(base & 255);
    const float* src = (k < 128) ? (emb + (long)i * 128 + k) : (x + (long)i * 128 + (k - 128));
    float4 v = *(const float4*)src;
    ushort4 o;
    o.x = f2b(v.x); o.y = f2b(v.y); o.z = f2b(v.z); o.w = f2b(v.w);
    *(ushort4*)(h0b + base) = o;
}

// ---------- aggregation on bf16 rows (commuted before GEMM) ----------
// out[i] = bf16( dinv_i * (sum_c dinv_c * h[c]) + dinv_i^2 * h[i] )
__global__ __launch_bounds__(256) void aggregate_b(const u16* __restrict__ h, const int* __restrict__ offs,
                                                   const int* __restrict__ scol, const float* __restrict__ dinv,
                                                   u16* __restrict__ out, int N) {
    int node = blockIdx.x * 4 + (threadIdx.x >> 6);
    int lane = threadIdx.x & 63;
    if (node >= N) return;
    int beg = offs[node], end = offs[node + 1];
    float a0 = 0.f, a1 = 0.f, a2 = 0.f, a3 = 0.f;
    int j = beg;
    for (; j + 1 < end; j += 2) {    // 2 gather rows in flight
        int c0 = scol[j], c1 = scol[j + 1];
        float d0 = dinv[c0], d1 = dinv[c1];
        ushort4 v0 = *(const ushort4*)(h + (long)c0 * 256 + lane * 4);
        ushort4 v1 = *(const ushort4*)(h + (long)c1 * 256 + lane * 4);
        a0 = fmaf(b2f(v0.x), d0, a0); a1 = fmaf(b2f(v0.y), d0, a1);
        a2 = fmaf(b2f(v0.z), d0, a2); a3 = fmaf(b2f(v0.w), d0, a3);
        a0 = fmaf(b2f(v1.x), d1, a0); a1 = fmaf(b2f(v1.y), d1, a1);
        a2 = fmaf(b2f(v1.z), d1, a2); a3 = fmaf(b2f(v1.w), d1, a3);
    }
    if (j < end) {
        int c0 = scol[j];
        float d0 = dinv[c0];
        ushort4 v0 = *(const ushort4*)(h + (long)c0 * 256 + lane * 4);
        a0 = fmaf(b2f(v0.x), d0, a0); a1 = fmaf(b2f(v0.y), d0, a1);
        a2 = fmaf(b2f(v0.z), d0, a2); a3 = fmaf(b2f(v0.w), d0, a3);
    }
    float di = dinv[node];
    ushort4 mv = *(const ushort4*)(h + (long)node * 256 + lane * 4);
    ushort4 o;
    o.x = f2b(di * fmaf(di, b2f(mv.x), a0));
    o.y = f2b(di * fmaf(di, b2f(mv.y), a1));
    o.z = f2b(di * fmaf(di, b2f(mv.z), a2));
    o.w = f2b(di * fmaf(di, b2f(mv.w), a3));
    *(ushort4*)(out + (long)node * 256 + lane * 4) = o;
}

// ---------- GEMM: C[M][256] = A_bf16[M][256] @ B + bias, BT_bf16[n][k] ----------
// block: 256 thr = 4 waves, tile 64(M) x 256(N), BK=64
template <int BF16OUT>
__global__ __launch_bounds__(256) void gemm_k256(const u16* __restrict__ A, const u16* __restrict__ BT,
                                                 const float* __restrict__ bias, void* __restrict__ C, int M) {
    __shared__ u16 As[64 * 72];     // +8 pad
    __shared__ u16 Bs[256 * 72];
    int tid = threadIdx.x;
    int wave = tid >> 6, lane = tid & 63, l15 = lane & 15, quad = lane >> 4;
    int row0 = blockIdx.x * 64;
    floatx4 acc[16];
    floatx4 zero = {0.f, 0.f, 0.f, 0.f};
#pragma unroll
    for (int i = 0; i < 16; i++) acc[i] = zero;

    int ar = tid >> 2, aseg = (tid & 3) * 16;
    int agrow = min(row0 + ar, M - 1);

    for (int k0 = 0; k0 < 256; k0 += 64) {
        {
            const uint4* s = (const uint4*)(A + (long)agrow * 256 + k0 + aseg);
            uint4* d = (uint4*)(As + ar * 72 + aseg);
            d[0] = s[0]; d[1] = s[1];
        }
        {
            const uint4* s = (const uint4*)(BT + (long)tid * 256 + k0);
            uint4* d = (uint4*)(Bs + tid * 72);
#pragma unroll
            for (int i = 0; i < 8; i++) d[i] = s[i];
        }
        __syncthreads();
#pragma unroll
        for (int kk = 0; kk < 64; kk += 32) {
            short8 a = *(const short8*)(As + (wave * 16 + l15) * 72 + kk + quad * 8);
#pragma unroll
            for (int nt = 0; nt < 16; nt++) {
                short8 b = *(const short8*)(Bs + (nt * 16 + l15) * 72 + kk + quad * 8);
                acc[nt] = __builtin_amdgcn_mfma_f32_16x16x32_bf16(a, b, acc[nt], 0, 0, 0);
            }
        }
        __syncthreads();
    }
    int mb = row0 + wave * 16 + quad * 4;
#pragma unroll
    for (int nt = 0; nt < 16; nt++) {
        int colc = nt * 16 + l15;
        float bv = bias[colc];
#pragma unroll
        for (int r = 0; r < 4; r++) {
            int mm = mb + r;
            if (mm < M) {
                float val = acc[nt][r] + bv;
                if (BF16OUT) ((u16*)C)[(long)mm * 256 + colc] = f2b(val);
                else         ((float*)C)[(long)mm * 256 + colc] = val;
            }
        }
    }
}

// ---------- BN stats: per-block partial column sums ----------
__global__ __launch_bounds__(256) void bn_stats(const float* __restrict__ h, float* __restrict__ sums, int N) {
    int j = threadIdx.x;                 // feature 0..255
    int r0 = blockIdx.x * 64;
    int r1 = min(r0 + 64, N);
    float s = 0.f, s2 = 0.f;
    for (int r = r0; r < r1; r++) {
        float v = h[(long)r * 256 + j];
        s += v;
        s2 = fmaf(v, v, s2);
    }
    unsafeAtomicAdd(&sums[j], s);
    unsafeAtomicAdd(&sums[256 + j], s2);
}

// ---------- BN apply + ReLU -> bf16 ----------
__global__ __launch_bounds__(256) void bn_apply(const float* __restrict__ h, const float* __restrict__ sums,
                                                const float* __restrict__ gamma, const float* __restrict__ beta,
                                                u16* __restrict__ hb, int N) {
    int t = blockIdx.x * 256 + threadIdx.x;
    long base = (long)t * 4;
    if (base >= (long)N * 256) return;
    int k = (int)(base & 255);
    float invN = 1.0f / (float)N;
    float4 v = *(const float4*)(h + base);
    ushort4 o;
    float vv[4] = {v.x, v.y, v.z, v.w};
    u16 ob[4];
#pragma unroll
    for (int i = 0; i < 4; i++) {
        int kk = k + i;
        float mean = sums[kk] * invN;
        float var = sums[256 + kk] * invN - mean * mean;
        float rs = rsqrtf(var + 1e-5f);
        float val = (vv[i] - mean) * rs * gamma[kk] + beta[kk];
        ob[i] = f2b(fmaxf(val, 0.f));
    }
    o.x = ob[0]; o.y = ob[1]; o.z = ob[2]; o.w = ob[3];
    *(ushort4*)(hb + base) = o;
}

// ---------- fused link predictor v2: register-Z, small LDS, high occupancy ----------
// block = 4 waves x 16 queries; Z fragments built directly in A-frag register layout
__global__ __launch_bounds__(256, 3) void predictor(const u16* __restrict__ h2b, const int* __restrict__ e0,
                                                    const int* __restrict__ e1, const u16* __restrict__ pW1T,
                                                    const float* __restrict__ pb1, const float* __restrict__ pW2,
                                                    const float* __restrict__ pb2, float* __restrict__ out, int Q) {
    __shared__ u16 Bs[256 * 40];   // 32-k slab, +8 pad (20.5 KB)
    int tid = threadIdx.x;
    int wave = tid >> 6, lane = tid & 63, l15 = lane & 15, quad = lane >> 4;
    int q0 = blockIdx.x * 64;
    int q = min(q0 + wave * 16 + l15, Q - 1);
    long u = (long)e0[q] * 256, v = (long)e1[q] * 256;
    // zreg[ki] = A-fragment for k-window ki: lane (l15,quad) holds z[l15][ki*32+quad*8 ..+8]
    short8 zreg[8];
#pragma unroll
    for (int i = 0; i < 8; i++) {
        uint4 a = *(const uint4*)(h2b + u + i * 32 + quad * 8);
        uint4 b = *(const uint4*)(h2b + v + i * 32 + quad * 8);
        uint4 z;
        z.x = pkmul(a.x, b.x);
        z.y = pkmul(a.y, b.y);
        z.z = pkmul(a.z, b.z);
        z.w = pkmul(a.w, b.w);
        zreg[i] = *(short8*)&z;
    }
    floatx4 acc[16];
    floatx4 zero = {0.f, 0.f, 0.f, 0.f};
#pragma unroll
    for (int i = 0; i < 16; i++) acc[i] = zero;

    for (int ki = 0; ki < 8; ki++) {
        {   // stage 32-k slab of pW1T: thread t = n-row
            const uint4* s = (const uint4*)(pW1T + (long)tid * 256 + ki * 32);
            uint4* d = (uint4*)(Bs + tid * 40);
            d[0] = s[0]; d[1] = s[1]; d[2] = s[2]; d[3] = s[3];
        }
        __syncthreads();
        short8 a = zreg[ki];
#pragma unroll
        for (int nt = 0; nt < 16; nt++) {
            short8 b = *(const short8*)(Bs + (nt * 16 + l15) * 40 + quad * 8);
            acc[nt] = __builtin_amdgcn_mfma_f32_16x16x32_bf16(a, b, acc[nt], 0, 0, 0);
        }
        __syncthreads();
    }
    // epilogue: out[q] = sigmoid( sum_n relu(z1[q][n]) * pW2[n] + pb2 )
    // C layout: col = nt*16+l15, row (query within wave tile) = quad*4 + r
    float rs0 = 0.f, rs1 = 0.f, rs2 = 0.f, rs3 = 0.f;
#pragma unroll
    for (int nt = 0; nt < 16; nt++) {
        int colc = nt * 16 + l15;
        float w2 = pW2[colc], bb = pb1[colc];
        float z;
        z = acc[nt][0] + bb; rs0 = fmaf(fmaxf(z, 0.f), w2, rs0);
        z = acc[nt][1] + bb; rs1 = fmaf(fmaxf(z, 0.f), w2, rs1);
        z = acc[nt][2] + bb; rs2 = fmaf(fmaxf(z, 0.f), w2, rs2);
        z = acc[nt][3] + bb; rs3 = fmaf(fmaxf(z, 0.f), w2, rs3);
    }
#pragma unroll
    for (int m = 1; m < 16; m <<= 1) {
        rs0 += __shfl_xor(rs0, m, 64);
        rs1 += __shfl_xor(rs1, m, 64);
        rs2 += __shfl_xor(rs2, m, 64);
        rs3 += __shfl_xor(rs3, m, 64);
    }
    if (l15 == 0) {
        int qb = q0 + wave * 16 + quad * 4;
        float b2v = pb2[0];
        float rr[4] = {rs0, rs1, rs2, rs3};
#pragma unroll
        for (int r = 0; r < 4; r++) {
            int qq = qb + r;
            if (qq < Q) out[qq] = 1.0f / (1.0f + __expf(-(rr[r] + b2v)));
        }
    }
}

extern "C" void kernel_launch(void* const* d_in, const int* in_sizes, int n_in,
                              void* d_out, int out_size, void* d_ws, size_t ws_size,
                              hipStream_t stream) {
    const float* x      = (const float*)d_in[0];
    const int*   adj_row= (const int*)d_in[1];
    const int*   adj_col= (const int*)d_in[2];
    const int*   edges  = (const int*)d_in[3];
    const float* emb    = (const float*)d_in[4];
    const float* W1     = (const float*)d_in[5];
    const float* b1     = (const float*)d_in[6];
    const float* W2     = (const float*)d_in[7];
    const float* b2     = (const float*)d_in[8];
    const float* gamma  = (const float*)d_in[9];
    const float* beta   = (const float*)d_in[10];
    const float* pW1    = (const float*)d_in[11];
    const float* pb1    = (const float*)d_in[12];
    const float* pW2    = (const float*)d_in[13];
    const float* pb2    = (const float*)d_in[14];
    float* out = (float*)d_out;

    int N = in_sizes[0] / 128;
    int E = in_sizes[1];
    int Q = in_sizes[3] / 2;

    char* ws = (char*)d_ws;
    size_t off = 0;
    auto alloc = [&](size_t bytes) -> char* {
        char* p = ws + off;
        off += (bytes + 255) & ~(size_t)255;
        return p;
    };
    int*   deg_cnt = (int*)alloc((size_t)N * 4);
    int*   offs    = (int*)alloc((size_t)(N + 1) * 4);
    int*   cursor  = (int*)alloc((size_t)N * 4);
    float* dinv    = (float*)alloc((size_t)N * 4);
    int*   scol    = (int*)alloc((size_t)E * 4);
    float* sums    = (float*)alloc(512 * 4);
    u16*   WT      = (u16*)alloc((size_t)3 * 65536 * 2);
    u16*   bufA    = (u16*)alloc((size_t)N * 256 * 2);   // h0b -> h1b -> h2b
    u16*   bufB    = (u16*)alloc((size_t)N * 256 * 2);   // agg output
    float* hraw    = (float*)alloc((size_t)N * 256 * 4); // h1 fp32 (pre-BN)

    hipMemsetAsync(deg_cnt, 0, (size_t)N * 4, stream);
    hipMemsetAsync(cursor, 0, (size_t)N * 4, stream);
    hipMemsetAsync(sums, 0, 512 * 4, stream);

    int eb  = (E + 255) / 256;
    int nb4 = (N * 64 + 255) / 256;
    int gb  = (N + 63) / 64;
    int ab  = (N + 3) / 4;

    count_deg<<<eb, 256, 0, stream>>>(adj_row, deg_cnt, E);
    scan_offsets<<<1, 1024, 0, stream>>>(deg_cnt, offs, dinv, N, E);
    sort_edges<<<eb, 256, 0, stream>>>(adj_row, adj_col, offs, cursor, scol, E);
    prep_w<<<768, 256, 0, stream>>>(W1, W2, pW1, WT);
    concat_h0<<<nb4, 256, 0, stream>>>(emb, x, bufA, N);

    // conv1 (commuted): agg(h0) @ W1 + b1
    aggregate_b<<<ab, 256, 0, stream>>>(bufA, offs, scol, dinv, bufB, N);
    gemm_k256<0><<<gb, 256, 0, stream>>>(bufB, WT, b1, hraw, N);
    bn_stats<<<(N + 63) / 64, 256, 0, stream>>>(hraw, sums, N);
    bn_apply<<<nb4, 256, 0, stream>>>(hraw, sums, gamma, beta, bufA, N);   // h1b
    // conv2 (commuted): agg(h1) @ W2 + b2 -> bf16 h2b
    aggregate_b<<<ab, 256, 0, stream>>>(bufA, offs, scol, dinv, bufB, N);
    gemm_k256<1><<<gb, 256, 0, stream>>>(bufB, WT + 65536, b2, bufA, N);   // h2b in bufA
    predictor<<<(Q + 63) / 64, 256, 0, stream>>>(bufA, edges, edges + Q,
                                                 WT + 131072, pb1, pW2, pb2, out, Q);
}

// Round 3
// 449.276 us; speedup vs baseline: 1.4320x; 1.3316x over previous
//
#include <hip/hip_runtime.h>

typedef unsigned short u16;
typedef unsigned int u32;
typedef __attribute__((ext_vector_type(8))) short short8;
typedef __attribute__((ext_vector_type(4))) float floatx4;

// ---------- bf16 helpers ----------
__device__ __forceinline__ float b2f(u32 bits) { union { u32 u; float f; } c; c.u = bits << 16; return c.f; }
__device__ __forceinline__ u16 f2b(float f) {
    union { float f; u32 u; } c; c.f = f;
    u32 u = c.u;
    return (u16)((u + 0x7FFFu + ((u >> 16) & 1u)) >> 16);   // RNE
}
// packed bf16 mul of u32 pairs, round-half-up (bias ~2^-16 rel, 2x cheaper than RNE)
__device__ __forceinline__ u32 pkmul(u32 a, u32 b) {
    union { u32 u; float f; } alo, ahi, blo, bhi, rlo, rhi;
    alo.u = a << 16; ahi.u = a & 0xFFFF0000u;
    blo.u = b << 16; bhi.u = b & 0xFFFF0000u;
    rlo.f = alo.f * blo.f; rhi.f = ahi.f * bhi.f;
    u32 lo = rlo.u + 0x8000u, hi = rhi.u + 0x8000u;
    return __builtin_amdgcn_perm(hi, lo, 0x07060302u);   // [lo>>16, hi>>16]
}

// ---------- graph prep ----------
__global__ __launch_bounds__(256) void count_deg(const int* __restrict__ row, int* __restrict__ cnt, int E) {
    int e = blockIdx.x * 256 + threadIdx.x;
    if (e < E) atomicAdd(&cnt[row[e]], 1);
}

__global__ __launch_bounds__(256) void deg_psum(const int* __restrict__ cnt, int* __restrict__ bsum, int N) {
    __shared__ int sc[256];
    int t = threadIdx.x, i = blockIdx.x * 256 + t;
    sc[t] = (i < N) ? cnt[i] : 0;
    __syncthreads();
    for (int o = 128; o > 0; o >>= 1) {
        if (t < o) sc[t] += sc[t + o];
        __syncthreads();
    }
    if (t == 0) bsum[blockIdx.x] = sc[0];
}

__global__ __launch_bounds__(256) void scan_bsum(const int* __restrict__ bsum, int* __restrict__ ebsum,
                                                 int NB, int* __restrict__ offs, int N, int E) {
    __shared__ int sc[256];
    int t = threadIdx.x;
    int v = (t < NB) ? bsum[t] : 0;
    sc[t] = v;
    __syncthreads();
    for (int o = 1; o < 256; o <<= 1) {
        int u = (t >= o) ? sc[t - o] : 0;
        __syncthreads();
        sc[t] += u;
        __syncthreads();
    }
    if (t < NB) ebsum[t] = sc[t] - v;
    if (t == 0) offs[N] = E;
}

__global__ __launch_bounds__(256) void write_offs(const int* __restrict__ cnt, const int* __restrict__ ebsum,
                                                  int* __restrict__ offs, float* __restrict__ dinv, int N) {
    __shared__ int sc[256];
    int t = threadIdx.x, i = blockIdx.x * 256 + t;
    int v = (i < N) ? cnt[i] : 0;
    sc[t] = v;
    __syncthreads();
    for (int o = 1; o < 256; o <<= 1) {
        int u = (t >= o) ? sc[t - o] : 0;
        __syncthreads();
        sc[t] += u;
        __syncthreads();
    }
    if (i < N) {
        offs[i] = ebsum[blockIdx.x] + sc[t] - v;
        dinv[i] = rsqrtf((float)v + 1.0f);
    }
}

__global__ __launch_bounds__(256) void sort_edges(const int* __restrict__ row, const int* __restrict__ col,
                                                  const int* __restrict__ offs, int* __restrict__ cursor,
                                                  int* __restrict__ scol, int E) {
    int e = blockIdx.x * 256 + threadIdx.x;
    if (e < E) {
        int r = row[e];
        int p = offs[r] + atomicAdd(&cursor[r], 1);
        scol[p] = col[e];
    }
}

// ---------- weight prep: WT[which][n][k] = bf16(W[k][n]) ----------
__global__ __launch_bounds__(256) void prep_w(const float* __restrict__ W1, const float* __restrict__ W2,
                                              const float* __restrict__ pW1, u16* __restrict__ WT) {
    int tid = blockIdx.x * 256 + threadIdx.x;
    int which = tid >> 16, id = tid & 65535;
    int n = id >> 8, k = id & 255;
    const float* W = (which == 0) ? W1 : ((which == 1) ? W2 : pW1);
    WT[tid] = f2b(W[k * 256 + n]);
}

// ---------- h0 = bf16(concat(emb, x)) ----------
__global__ __launch_bounds__(256) void concat_h0(const float* __restrict__ emb, const float* __restrict__ x,
                                                 u16* __restrict__ h0b, int N) {
    int t = blockIdx.x * 256 + threadIdx.x;
    long base = (long)t * 4;
    if (base >= (long)N * 256) return;
    int i = (int)(base >> 8), k = (int)(base & 255);
    const float* src = (k < 128) ? (emb + (long)i * 128 + k) : (x + (long)i * 128 + (k - 128));
    float4 v = *(const float4*)src;
    ushort4 o;
    o.x = f2b(v.x); o.y = f2b(v.y); o.z = f2b(v.z); o.w = f2b(v.w);
    *(ushort4*)(h0b + base) = o;
}

// ---------- aggregation on bf16 rows ----------
// out[i] = bf16( dinv_i * (sum_c dinv_c * h[c] + dinv_i * h[i]) )
__global__ __launch_bounds__(256) void aggregate_b(const u16* __restrict__ h, const int* __restrict__ offs,
                                                   const int* __restrict__ scol, const float* __restrict__ dinv,
                                                   u16* __restrict__ out, int N) {
    int node = blockIdx.x * 4 + (threadIdx.x >> 6);
    int lane = threadIdx.x & 63;
    if (node >= N) return;
    int beg = offs[node], end = offs[node + 1];
    float a0 = 0.f, a1 = 0.f, a2 = 0.f, a3 = 0.f;
    int j = beg;
    for (; j + 3 < end; j += 4) {    // 4 gather rows in flight
        int c0 = scol[j], c1 = scol[j + 1], c2 = scol[j + 2], c3 = scol[j + 3];
        float d0 = dinv[c0], d1 = dinv[c1], d2 = dinv[c2], d3 = dinv[c3];
        ushort4 v0 = *(const ushort4*)(h + (long)c0 * 256 + lane * 4);
        ushort4 v1 = *(const ushort4*)(h + (long)c1 * 256 + lane * 4);
        ushort4 v2 = *(const ushort4*)(h + (long)c2 * 256 + lane * 4);
        ushort4 v3 = *(const ushort4*)(h + (long)c3 * 256 + lane * 4);
        a0 = fmaf(b2f(v0.x), d0, a0); a1 = fmaf(b2f(v0.y), d0, a1);
        a2 = fmaf(b2f(v0.z), d0, a2); a3 = fmaf(b2f(v0.w), d0, a3);
        a0 = fmaf(b2f(v1.x), d1, a0); a1 = fmaf(b2f(v1.y), d1, a1);
        a2 = fmaf(b2f(v1.z), d1, a2); a3 = fmaf(b2f(v1.w), d1, a3);
        a0 = fmaf(b2f(v2.x), d2, a0); a1 = fmaf(b2f(v2.y), d2, a1);
        a2 = fmaf(b2f(v2.z), d2, a2); a3 = fmaf(b2f(v2.w), d2, a3);
        a0 = fmaf(b2f(v3.x), d3, a0); a1 = fmaf(b2f(v3.y), d3, a1);
        a2 = fmaf(b2f(v3.z), d3, a2); a3 = fmaf(b2f(v3.w), d3, a3);
    }
    for (; j < end; j++) {
        int c0 = scol[j];
        float d0 = dinv[c0];
        ushort4 v0 = *(const ushort4*)(h + (long)c0 * 256 + lane * 4);
        a0 = fmaf(b2f(v0.x), d0, a0); a1 = fmaf(b2f(v0.y), d0, a1);
        a2 = fmaf(b2f(v0.z), d0, a2); a3 = fmaf(b2f(v0.w), d0, a3);
    }
    float di = dinv[node];
    ushort4 mv = *(const ushort4*)(h + (long)node * 256 + lane * 4);
    ushort4 o;
    o.x = f2b(di * fmaf(di, b2f(mv.x), a0));
    o.y = f2b(di * fmaf(di, b2f(mv.y), a1));
    o.z = f2b(di * fmaf(di, b2f(mv.z), a2));
    o.w = f2b(di * fmaf(di, b2f(mv.w), a3));
    *(ushort4*)(out + (long)node * 256 + lane * 4) = o;
}

// ---------- GEMM v2: C_bf16[M][256] = A_bf16[M][256] @ B + bias ----------
// 512 thr = 8 waves, 256 rows/block (32/wave), B staged ONCE (2 phases x 64KB, xor-swizzle)
__global__ __launch_bounds__(512, 2) void gemm_big(const u16* __restrict__ A, const u16* __restrict__ BT,
                                                   const float* __restrict__ bias, u16* __restrict__ C, int M) {
    __shared__ u16 Bs[128 * 256];   // 64 KB
    int tid = threadIdx.x;
    int wave = tid >> 6, lane = tid & 63, l15 = lane & 15, quad = lane >> 4;
    int r0 = blockIdx.x * 256 + wave * 32;
    // A fragments in registers: za[g][ki], lane holds A[m=l15][k=ki*32+quad*8 ..+8]
    short8 za[2][8];
#pragma unroll
    for (int g = 0; g < 2; g++) {
        long row = min(r0 + g * 16 + l15, M - 1);
#pragma unroll
        for (int ki = 0; ki < 8; ki++)
            za[g][ki] = *(const short8*)(A + row * 256 + ki * 32 + quad * 8);
    }
    floatx4 acc[2][16];
    floatx4 zero = {0.f, 0.f, 0.f, 0.f};
#pragma unroll
    for (int g = 0; g < 2; g++)
#pragma unroll
        for (int j = 0; j < 16; j++) acc[g][j] = zero;

    for (int p = 0; p < 2; p++) {
        {   // stage 128 n-rows of BT, 16B chunks xor-swizzled by (n&7)
            int nl = tid >> 2, cg = (tid & 3) * 8;
            const uint4* src = (const uint4*)(BT + (long)(p * 128 + nl) * 256);
#pragma unroll
            for (int c8 = 0; c8 < 8; c8++) {
                int c = cg + c8;
                int cs = c ^ (nl & 7);
                *(uint4*)(Bs + nl * 256 + cs * 8) = src[c];
            }
        }
        __syncthreads();
#pragma unroll
        for (int ki = 0; ki < 8; ki++) {
#pragma unroll
            for (int nt = 0; nt < 8; nt++) {
                int nl = nt * 16 + l15;
                int cs = (ki * 4 + quad) ^ (l15 & 7);
                short8 b = *(const short8*)(Bs + nl * 256 + cs * 8);
                acc[0][p * 8 + nt] = __builtin_amdgcn_mfma_f32_16x16x32_bf16(za[0][ki], b, acc[0][p * 8 + nt], 0, 0, 0);
                acc[1][p * 8 + nt] = __builtin_amdgcn_mfma_f32_16x16x32_bf16(za[1][ki], b, acc[1][p * 8 + nt], 0, 0, 0);
            }
        }
        __syncthreads();
    }
#pragma unroll
    for (int g = 0; g < 2; g++)
#pragma unroll
        for (int j = 0; j < 16; j++) {
            int col = (j >> 3) * 128 + (j & 7) * 16 + l15;
            float bv = bias[col];
#pragma unroll
            for (int r = 0; r < 4; r++) {
                int row = r0 + g * 16 + quad * 4 + r;
                if (row < M) C[(long)row * 256 + col] = f2b(acc[g][j][r] + bv);
            }
        }
}

// ---------- BN stats on bf16 h1 ----------
__global__ __launch_bounds__(256) void bn_stats_b(const u16* __restrict__ h, float* __restrict__ sums, int N) {
    int col = threadIdx.x;
    int r0 = blockIdx.x * 128, r1 = min(r0 + 128, N);
    float s = 0.f, s2 = 0.f;
    for (int r = r0; r < r1; r++) {
        float v = b2f(h[(long)r * 256 + col]);
        s += v;
        s2 = fmaf(v, v, s2);
    }
    unsafeAtomicAdd(&sums[col], s);
    unsafeAtomicAdd(&sums[256 + col], s2);
}

// ---------- BN apply + ReLU (bf16 -> bf16) ----------
__global__ __launch_bounds__(256) void bn_apply_b(const u16* __restrict__ h, const float* __restrict__ sums,
                                                  const float* __restrict__ gamma, const float* __restrict__ beta,
                                                  u16* __restrict__ o, int N) {
    long t = (long)blockIdx.x * 256 + threadIdx.x;
    long base = t * 4;
    if (base >= (long)N * 256) return;
    int k = (int)(base & 255);
    float invN = 1.0f / (float)N;
    ushort4 v = *(const ushort4*)(h + base);
    u16 vv[4] = {v.x, v.y, v.z, v.w};
    u16 ob[4];
#pragma unroll
    for (int i = 0; i < 4; i++) {
        int kk = k + i;
        float mean = sums[kk] * invN;
        float var = sums[256 + kk] * invN - mean * mean;
        float rs = rsqrtf(var + 1e-5f);
        float val = (b2f(vv[i]) - mean) * rs * gamma[kk] + beta[kk];
        ob[i] = f2b(fmaxf(val, 0.f));
    }
    ushort4 ov; ov.x = ob[0]; ov.y = ob[1]; ov.z = ob[2]; ov.w = ob[3];
    *(ushort4*)(o + base) = ov;
}

// ---------- predictor v3: B staged once, register A-frags, full-n in wave ----------
__global__ __launch_bounds__(512, 2) void predictor(const u16* __restrict__ h2b, const int* __restrict__ e0,
                                                    const int* __restrict__ e1, const u16* __restrict__ pW1T,
                                                    const float* __restrict__ pb1, const float* __restrict__ pW2,
                                                    const float* __restrict__ pb2, float* __restrict__ out, int Q) {
    __shared__ u16 Bs[128 * 256];   // 64 KB
    int tid = threadIdx.x;
    int wave = tid >> 6, lane = tid & 63, l15 = lane & 15, quad = lane >> 4;
    int q0 = blockIdx.x * 256;
    // build Z fragments in registers: za[g][ki], query = q0 + wave*32 + g*16 + l15
    short8 za[2][8];
#pragma unroll
    for (int g = 0; g < 2; g++) {
        int q = min(q0 + wave * 32 + g * 16 + l15, Q - 1);
        long u = (long)e0[q] * 256, v = (long)e1[q] * 256;
#pragma unroll
        for (int ki = 0; ki < 8; ki++) {
            uint4 a = *(const uint4*)(h2b + u + ki * 32 + quad * 8);
            uint4 b = *(const uint4*)(h2b + v + ki * 32 + quad * 8);
            uint4 z;
            z.x = pkmul(a.x, b.x);
            z.y = pkmul(a.y, b.y);
            z.z = pkmul(a.z, b.z);
            z.w = pkmul(a.w, b.w);
            za[g][ki] = *(short8*)&z;
        }
    }
    floatx4 acc[2][16];
    floatx4 zero = {0.f, 0.f, 0.f, 0.f};
#pragma unroll
    for (int g = 0; g < 2; g++)
#pragma unroll
        for (int j = 0; j < 16; j++) acc[g][j] = zero;

    for (int p = 0; p < 2; p++) {
        {
            int nl = tid >> 2, cg = (tid & 3) * 8;
            const uint4* src = (const uint4*)(pW1T + (long)(p * 128 + nl) * 256);
#pragma unroll
            for (int c8 = 0; c8 < 8; c8++) {
                int c = cg + c8;
                int cs = c ^ (nl & 7);
                *(uint4*)(Bs + nl * 256 + cs * 8) = src[c];
            }
        }
        __syncthreads();
#pragma unroll
        for (int ki = 0; ki < 8; ki++) {
#pragma unroll
            for (int nt = 0; nt < 8; nt++) {
                int nl = nt * 16 + l15;
                int cs = (ki * 4 + quad) ^ (l15 & 7);
                short8 b = *(const short8*)(Bs + nl * 256 + cs * 8);
                acc[0][p * 8 + nt] = __builtin_amdgcn_mfma_f32_16x16x32_bf16(za[0][ki], b, acc[0][p * 8 + nt], 0, 0, 0);
                acc[1][p * 8 + nt] = __builtin_amdgcn_mfma_f32_16x16x32_bf16(za[1][ki], b, acc[1][p * 8 + nt], 0, 0, 0);
            }
        }
        __syncthreads();
    }
    // epilogue: out[q] = sigmoid( sum_col relu(acc + pb1[col]) * pW2[col] + pb2 )
    float rs[2][4] = {{0.f, 0.f, 0.f, 0.f}, {0.f, 0.f, 0.f, 0.f}};
#pragma unroll
    for (int g = 0; g < 2; g++)
#pragma unroll
        for (int j = 0; j < 16; j++) {
            int col = (j >> 3) * 128 + (j & 7) * 16 + l15;
            float w2 = pW2[col], bb = pb1[col];
#pragma unroll
            for (int r = 0; r < 4; r++)
                rs[g][r] = fmaf(fmaxf(acc[g][j][r] + bb, 0.f), w2, rs[g][r]);
        }
#pragma unroll
    for (int m = 1; m < 16; m <<= 1) {
#pragma unroll
        for (int g = 0; g < 2; g++)
#pragma unroll
            for (int r = 0; r < 4; r++)
                rs[g][r] += __shfl_xor(rs[g][r], m, 64);
    }
    if (l15 == 0) {
        float b2v = pb2[0];
#pragma unroll
        for (int g = 0; g < 2; g++)
#pragma unroll
            for (int r = 0; r < 4; r++) {
                int q = q0 + wave * 32 + g * 16 + quad * 4 + r;
                if (q < Q) out[q] = 1.0f / (1.0f + __expf(-(rs[g][r] + b2v)));
            }
    }
}

extern "C" void kernel_launch(void* const* d_in, const int* in_sizes, int n_in,
                              void* d_out, int out_size, void* d_ws, size_t ws_size,
                              hipStream_t stream) {
    const float* x      = (const float*)d_in[0];
    const int*   adj_row= (const int*)d_in[1];
    const int*   adj_col= (const int*)d_in[2];
    const int*   edges  = (const int*)d_in[3];
    const float* emb    = (const float*)d_in[4];
    const float* W1     = (const float*)d_in[5];
    const float* b1     = (const float*)d_in[6];
    const float* W2     = (const float*)d_in[7];
    const float* b2     = (const float*)d_in[8];
    const float* gamma  = (const float*)d_in[9];
    const float* beta   = (const float*)d_in[10];
    const float* pW1    = (const float*)d_in[11];
    const float* pb1    = (const float*)d_in[12];
    const float* pW2    = (const float*)d_in[13];
    const float* pb2    = (const float*)d_in[14];
    float* out = (float*)d_out;

    int N = in_sizes[0] / 128;
    int E = in_sizes[1];
    int Q = in_sizes[3] / 2;
    int NB = (N + 255) / 256;

    char* ws = (char*)d_ws;
    size_t off = 0;
    auto alloc = [&](size_t bytes) -> char* {
        char* p = ws + off;
        off += (bytes + 255) & ~(size_t)255;
        return p;
    };
    int*   deg_cnt = (int*)alloc((size_t)N * 4);
    int*   offs    = (int*)alloc((size_t)(N + 1) * 4);
    int*   cursor  = (int*)alloc((size_t)N * 4);
    float* dinv    = (float*)alloc((size_t)N * 4);
    int*   scol    = (int*)alloc((size_t)E * 4);
    float* sums    = (float*)alloc(512 * 4);
    int*   bsum    = (int*)alloc(256 * 4);
    int*   ebsum   = (int*)alloc(256 * 4);
    u16*   WT      = (u16*)alloc((size_t)3 * 65536 * 2);
    u16*   bufA    = (u16*)alloc((size_t)N * 256 * 2);
    u16*   bufB    = (u16*)alloc((size_t)N * 256 * 2);
    u16*   bufC    = (u16*)alloc((size_t)N * 256 * 2);

    hipMemsetAsync(deg_cnt, 0, (size_t)N * 4, stream);
    hipMemsetAsync(cursor, 0, (size_t)N * 4, stream);
    hipMemsetAsync(sums, 0, 512 * 4, stream);

    int eb  = (E + 255) / 256;
    int nb4 = (N * 64 + 255) / 256;
    int gb  = (N + 255) / 256;
    int ab  = (N + 3) / 4;

    count_deg<<<eb, 256, 0, stream>>>(adj_row, deg_cnt, E);
    deg_psum<<<NB, 256, 0, stream>>>(deg_cnt, bsum, N);
    scan_bsum<<<1, 256, 0, stream>>>(bsum, ebsum, NB, offs, N, E);
    write_offs<<<NB, 256, 0, stream>>>(deg_cnt, ebsum, offs, dinv, N);
    sort_edges<<<eb, 256, 0, stream>>>(adj_row, adj_col, offs, cursor, scol, E);
    prep_w<<<768, 256, 0, stream>>>(W1, W2, pW1, WT);
    concat_h0<<<nb4, 256, 0, stream>>>(emb, x, bufA, N);

    // conv1 (commuted): h1 = agg(h0) @ W1 + b1  (bf16 out)
    aggregate_b<<<ab, 256, 0, stream>>>(bufA, offs, scol, dinv, bufB, N);
    gemm_big<<<gb, 512, 0, stream>>>(bufB, WT, b1, bufC, N);
    bn_stats_b<<<(N + 127) / 128, 256, 0, stream>>>(bufC, sums, N);
    bn_apply_b<<<nb4, 256, 0, stream>>>(bufC, sums, gamma, beta, bufA, N);   // h1n
    // conv2 (commuted): h2 = agg(h1n) @ W2 + b2  (bf16 out)
    aggregate_b<<<ab, 256, 0, stream>>>(bufA, offs, scol, dinv, bufB, N);
    gemm_big<<<gb, 512, 0, stream>>>(bufB, WT + 65536, b2, bufC, N);
    // link predictor
    predictor<<<(Q + 255) / 256, 512, 0, stream>>>(bufC, edges, edges + Q,
                                                   WT + 131072, pb1, pW2, pb2, out, Q);
}